// Round 17
// baseline (145.461 us; speedup 1.0000x reference)
//
#include <hip/hip_runtime.h>
#include <math.h>

#define B_      64
#define S_      128
#define KN      16
#define EE      128
#define HH      100
#define NTREE   8192            // B_*S_

typedef __attribute__((ext_vector_type(8))) short   bf8;    // 8 bf16 (4 VGPRs)
typedef __attribute__((ext_vector_type(2))) float   f32x2;
typedef __attribute__((ext_vector_type(4))) float   f32x4;
typedef __attribute__((ext_vector_type(4))) unsigned int u32x4;

// workspace byte offsets (256-aligned)
#define EMB_BF_OFF   0u           // 50000*128*2 = 12,800,000
#define WC_BF_OFF    12800000u    // 128*128*2   = 32,768
#define WIH_BF_OFF   12832768u    // 768*128*2   = 196,608 (padded [dir][g][128j][128k])
#define WHH_BF_OFF   13029376u    // 768*128*2   = 196,608 (padded, zero pads)
#define ENC_BF_OFF   13225984u    // 16384*128*2 = 4,194,304   rows = e*8192 + t*64 + b
#define HMAX_OFF     17420288u    // 25600*4     = 102,400

__constant__ float c_cnt[16] = {16.f,8.f,7.f,4.f,3.f,3.f,3.f,2.f,
                                1.f,1.f,1.f,1.f,1.f,1.f,1.f,1.f};

__device__ __forceinline__ float bf2f(unsigned short u) {
    unsigned int x = ((unsigned int)u) << 16;
    return __builtin_bit_cast(float, x);
}
__device__ __forceinline__ unsigned short f2bf(float f) {
    unsigned int x = __builtin_bit_cast(unsigned int, f);
    x = x + 0x7fffu + ((x >> 16) & 1u);          // RNE
    return (unsigned short)(x >> 16);
}
__device__ __forceinline__ f32x2 up2(unsigned int u) {
    f32x2 v;
    v[0] = bf2f((unsigned short)(u & 0xffffu));
    v[1] = bf2f((unsigned short)(u >> 16));
    return v;
}
__device__ __forceinline__ unsigned int pack2(const f32x2& v) {
    return (unsigned int)f2bf(v[0]) | ((unsigned int)f2bf(v[1]) << 16);
}
__device__ __forceinline__ float selq(const f32x4& v, int q) {
    const float a = (q & 1) ? v[1] : v[0];
    const float b = (q & 1) ? v[3] : v[2];
    return (q & 2) ? b : a;
}
// swizzle a 16B-aligned column-byte offset within a 256B row
#define SWZ(row, cb) ((cb) ^ (((row) & 7) << 4))

// ---------------------------------------------------------------------------
// K0: fp32 -> bf16 prep: emb + Wc + wih/whh padded [2][3][128j][128k].
// ---------------------------------------------------------------------------
#define NA 1600000   // emb float4s
#define NB 4096      // Wc float4s
#define NC 24576     // wih_pad ushort4s (768*128/4)
#define ND 24576     // whh_pad ushort4s
__global__ __launch_bounds__(256) void k_prep(
    const float* __restrict__ emb, const float* __restrict__ Wc,
    const float* __restrict__ wih_f, const float* __restrict__ wih_b,
    const float* __restrict__ whh_f, const float* __restrict__ whh_b,
    unsigned short* __restrict__ emb_bf, unsigned short* __restrict__ wc_bf,
    unsigned short* __restrict__ wih_pad, unsigned short* __restrict__ whh_pad)
{
    const int i = blockIdx.x * 256 + threadIdx.x;
    if (i < NA + NB) {
        const float* src = (i < NA) ? emb : Wc;
        unsigned short* dst = (i < NA) ? emb_bf : wc_bf;
        const int j = (i < NA) ? i : i - NA;
        float4 v = ((const float4*)src)[j];
        ushort4 o;
        o.x = f2bf(v.x); o.y = f2bf(v.y); o.z = f2bf(v.z); o.w = f2bf(v.w);
        ((ushort4*)dst)[j] = o;
    } else if (i < NA + NB + NC) {
        const int u = i - NA - NB;                  // 0..24575
        const int row = u >> 5, k4 = u & 31;        // row 0..767
        const int dir = row / 384, rem = row % 384, g = rem >> 7, j = rem & 127;
        ushort4 o = {0, 0, 0, 0};
        if (j < 100) {
            const float* w = dir ? wih_b : wih_f;   // [300][128]
            float4 v = ((const float4*)w)[(g * 100 + j) * 32 + k4];
            o.x = f2bf(v.x); o.y = f2bf(v.y); o.z = f2bf(v.z); o.w = f2bf(v.w);
        }
        ((ushort4*)wih_pad)[u] = o;
    } else if (i < NA + NB + NC + ND) {
        const int u = i - NA - NB - NC;
        const int row = u >> 5, k0 = (u & 31) * 4;
        const int dir = row / 384, rem = row % 384, g = rem >> 7, j = rem & 127;
        ushort4 o = {0, 0, 0, 0};
        if (j < 100) {
            const float* w = dir ? whh_b : whh_f;   // [300][100]
            const float* wr = w + (g * 100 + j) * 100;
            unsigned short t[4];
            #pragma unroll
            for (int q = 0; q < 4; ++q)
                t[q] = (k0 + q < 100) ? f2bf(wr[k0 + q]) : (unsigned short)0;
            o.x = t[0]; o.y = t[1]; o.z = t[2]; o.w = t[3];
        }
        ((ushort4*)whh_pad)[u] = o;
    }
}

// ---------------------------------------------------------------------------
// K1: REGISTER tree aggregation + bf16 emb gather. B operand (Wc) is read
// DIRECTLY from global (identical for all blocks -> L1/L2-hot) — no B_lds:
// LDS halves to 32KB (more blocks/CU), per-lane LDS ops drop 24r+8w -> 8r+4w.
// ---------------------------------------------------------------------------
__global__ __launch_bounds__(512) void k_encode(
    const int* __restrict__ tok1, const int* __restrict__ tok2,
    const unsigned short* __restrict__ emb_bf,
    const unsigned short* __restrict__ wc_bf,
    const float* __restrict__ bc,
    unsigned short* __restrict__ enc_bf)
{
    __shared__ unsigned short A_lds[128 * 128];   // [row][k] swizzled (32KB)
    const int tid = threadIdx.x;
    const int blk = blockIdx.x;
    const int e = blk >> 10;
    const int tree0 = (blk & 1023) * 8;
    const int* __restrict__ tok = e ? tok2 : tok1;

    const int lane = tid & 63;
    const int tr = tid >> 6;         // tree 0..7 (== wave)
    const int sd = tid & 63;         // 2-dim segment: dims [2*sd, 2*sd+1]

    // tokens (4 x int4 = all 16 nodes of this tree)
    const int4* tkp = (const int4*)(tok + (tree0 + tr) * KN);
    const int4 tkA = tkp[0], tkB = tkp[1], tkC = tkp[2], tkD = tkp[3];

    // gather 16 x u32 (2 bf16 dims each; 64 lanes x 4B = full row, coalesced)
#define LDE(tk) up2(*(const unsigned int*)(emb_bf + (size_t)(tk) * EE + sd * 2))
    f32x2 a0 = LDE(tkA.x), a1 = LDE(tkA.y), a2  = LDE(tkA.z), a3  = LDE(tkA.w);
    f32x2 a4 = LDE(tkB.x), a5 = LDE(tkB.y), a6  = LDE(tkB.z), a7  = LDE(tkB.w);
    f32x2 a8 = LDE(tkC.x), a9 = LDE(tkC.y), a10 = LDE(tkC.z), a11 = LDE(tkC.w);
    f32x2 a12 = LDE(tkD.x), a13 = LDE(tkD.y), a14 = LDE(tkD.z), a15 = LDE(tkD.w);
#undef LDE

    // bottom-up child-sum (pure VALU)
    a7 += a15;
    a3 += a7  + a8;   a4 += a9  + a10;
    a5 += a11 + a12;  a6 += a13 + a14;
    a1 += a3  + a4;   a2 += a5  + a6;
    a0 += a1  + a2;

    // write to A tile: 4B per node at swizzled chunk
    {
        const int cb = (sd >> 2) << 4;       // 16B chunk byte offset
        const int ib = (sd & 3) * 4;         // byte within chunk
        const int r0 = tr * 16;
#define STA(n, v) *(unsigned int*)((char*)A_lds + (r0 + (n)) * 256 \
                    + (cb ^ (((r0 + (n)) & 7) << 4)) + ib) = pack2(v);
        STA(0, a0)  STA(1, a1)  STA(2, a2)   STA(3, a3)
        STA(4, a4)  STA(5, a5)  STA(6, a6)   STA(7, a7)
        STA(8, a8)  STA(9, a9)  STA(10, a10) STA(11, a11)
        STA(12, a12) STA(13, a13) STA(14, a14) STA(15, a15)
#undef STA
    }
    __syncthreads();

    const int wid = tid >> 6;
    const int wr = wid >> 1, wc = wid & 1;
    const int l15 = lane & 15, lg = lane >> 4;

    f32x4 acc[2][4];
    #pragma unroll
    for (int rt = 0; rt < 2; ++rt)
        #pragma unroll
        for (int ct = 0; ct < 4; ++ct) acc[rt][ct] = (f32x4){0.f, 0.f, 0.f, 0.f};

    #pragma unroll
    for (int ks = 0; ks < 4; ++ks) {
        bf8 aF[2], bF[4];
        #pragma unroll
        for (int rt = 0; rt < 2; ++rt) {
            const int row = wr * 32 + rt * 16 + l15;
            aF[rt] = *(const bf8*)((const char*)A_lds + row * 256 + SWZ(row, ks * 64 + lg * 16));
        }
        #pragma unroll
        for (int ct = 0; ct < 4; ++ct) {
            const int col = wc * 64 + ct * 16 + l15;
            bF[ct] = *(const bf8*)(wc_bf + (size_t)col * EE + ks * 32 + lg * 8);
        }
        #pragma unroll
        for (int rt = 0; rt < 2; ++rt)
            #pragma unroll
            for (int ct = 0; ct < 4; ++ct)
                acc[rt][ct] = __builtin_amdgcn_mfma_f32_16x16x32_bf16(aF[rt], bF[ct], acc[rt][ct], 0, 0, 0);
    }

    #pragma unroll
    for (int rt = 0; rt < 2; ++rt) {
        const int ltree = wr * 2 + rt;
        #pragma unroll
        for (int ct = 0; ct < 4; ++ct) {
            const int col = wc * 64 + ct * 16 + l15;
            const float bcv = bc[col];
            f32x4 v = acc[rt][ct];
            float m = -1e30f;
            #pragma unroll
            for (int r = 0; r < 4; ++r)
                m = fmaxf(m, v[r] + c_cnt[lg * 4 + r] * bcv);
            m = fmaxf(m, __shfl_xor(m, 16));
            m = fmaxf(m, __shfl_xor(m, 32));
            m = fmaxf(m, 0.f);
            if (lg == 0) {
                const int gtree = tree0 + ltree;
                const int row = (gtree & 127) * 64 + (gtree >> 7);   // t*64 + b
                enc_bf[((size_t)e * NTREE + row) * EE + col] = f2bf(m);
            }
        }
    }
}

// ---------------------------------------------------------------------------
// K3: LDS-resident GRU scan (R13-exact: 64 blocks x 448 thr, 7 waves,
// eC/eN one-step-ahead enc prefetch, ih-first order, gate split).
// ---------------------------------------------------------------------------
__global__ __launch_bounds__(448, 2) void k_gru(
    const unsigned short* __restrict__ enc_bf,
    const unsigned short* __restrict__ wih_pad,
    const unsigned short* __restrict__ whh_pad,
    const float* __restrict__ bih_f, const float* __restrict__ bih_b,
    const float* __restrict__ bhh_f, const float* __restrict__ bhh_b,
    float* __restrict__ hmax_out)
{
    __shared__ unsigned char enc_lds[4 * 128 * 256];  // 128KB [c][t][chunk^(c<<2)]
    __shared__ unsigned char h_lds[2][4 * 256];       // 2KB dbuf, rotated chunks
    const int tid  = threadIdx.x;
    const int blk  = blockIdx.x;        // 64
    const int e    = blk >> 5;
    const int dir  = (blk >> 4) & 1;
    const int b0   = (blk & 15) * 4;
    const int lane = tid & 63;
    const int l15  = lane & 15;
    const int lg   = lane >> 4;
    const int c    = l15 & 3;           // seq column
    const int q    = l15 >> 2;          // owned r-slot (gate split)
    const int jbase = (tid >> 6) * 16;
    const int j_own = jbase + lg * 4 + q;

    for (int u = tid; u < 512; u += 448)
        ((unsigned int*)h_lds)[u] = 0u;

    // stage enc slice into LDS (content chunk = rc ^ (c<<2))
    #pragma unroll
    for (int i = 0; i < 19; ++i) {
        const int s = tid + i * 448;
        if (s < 8192) {
            const int sc = s >> 11, st = (s >> 4) & 127, rc = s & 15;
            const int gch = rc ^ (sc << 2);
            const u32x4 v = *(const u32x4*)(enc_bf
                + ((size_t)e * NTREE + st * 64 + b0 + sc) * EE + gch * 8);
            *(u32x4*)(enc_lds + s * 16) = v;
        }
    }

    // weight A-frags: row j = jbase + l15, k = ks*32 + lg*8
    bf8 aI[3][4], aH[3][4];
    {
        const unsigned short* wiP = wih_pad + (size_t)dir * 3 * 128 * 128;
        const unsigned short* whP = whh_pad + (size_t)dir * 3 * 128 * 128;
        #pragma unroll
        for (int g = 0; g < 3; ++g)
            #pragma unroll
            for (int ks = 0; ks < 4; ++ks) {
                const size_t ro = (size_t)(g * 128 + jbase + l15) * 128 + ks * 32 + lg * 8;
                aI[g][ks] = *(const bf8*)(wiP + ro);
                aH[g][ks] = *(const bf8*)(whP + ro);
            }
    }
    const float* __restrict__ bih = dir ? bih_b : bih_f;
    const float* __restrict__ bhh = dir ? bhh_b : bhh_f;
    f32x4 bR, bZ, bI_, bH_;
    #pragma unroll
    for (int r = 0; r < 4; ++r) {
        const int j = jbase + lg * 4 + r;
        bR[r]  = (j < 100) ? bih[j]       + bhh[j]       : 0.f;
        bZ[r]  = (j < 100) ? bih[100 + j] + bhh[100 + j] : 0.f;
        bI_[r] = (j < 100) ? bih[200 + j] : 0.f;
        bH_[r] = (j < 100) ? bhh[200 + j] : 0.f;
    }

    // constant per-lane LDS offsets
    unsigned int eoff[4], hoff[4];
    #pragma unroll
    for (int ks = 0; ks < 4; ++ks) {
        eoff[ks] = c * 32768 + ((((ks * 4 + lg) ^ (c << 2)) & 15) << 4);
        hoff[ks] = c * 256 + (((ks * 4 + lg + 4 * c) & 15) << 4);
    }
    const unsigned int hw_off = c * 256
        + ((((j_own >> 3) + 4 * c) & 15) << 4) + (j_own & 7) * 2;

    float h_cur = 0.f;
    float hmx   = -1e30f;
    __syncthreads();   // staging + h-zero complete (one-time drain)

    bf8 eC[4], eN[4];
    {
        const int tm = dir ? 127 : 0;
        #pragma unroll
        for (int ks = 0; ks < 4; ++ks)
            eC[ks] = *(const bf8*)(enc_lds + tm * 256 + eoff[ks]);
    }

#define L2E  1.4426950408889634f
#define GRU_STEP(EC, EN, P, S)                                                 \
    {                                                                          \
        bf8 hF[4];                                                             \
        _Pragma("unroll")                                                      \
        for (int ks = 0; ks < 4; ++ks)                                         \
            hF[ks] = *(const bf8*)(h_lds[P] + hoff[ks]);                       \
        f32x4 ar = bR, az = bZ, ai = bI_, ah = bH_;                            \
        _Pragma("unroll")                                                      \
        for (int ks = 0; ks < 4; ++ks) {                                       \
            ar = __builtin_amdgcn_mfma_f32_16x16x32_bf16(aI[0][ks], EC[ks], ar, 0, 0, 0); \
            az = __builtin_amdgcn_mfma_f32_16x16x32_bf16(aI[1][ks], EC[ks], az, 0, 0, 0); \
            ai = __builtin_amdgcn_mfma_f32_16x16x32_bf16(aI[2][ks], EC[ks], ai, 0, 0, 0); \
        }                                                                      \
        if ((S) + 1 < S_) {                                                    \
            const int tmn = dir ? (126 - (S)) : ((S) + 1);                     \
            _Pragma("unroll")                                                  \
            for (int ks = 0; ks < 4; ++ks)                                     \
                EN[ks] = *(const bf8*)(enc_lds + tmn * 256 + eoff[ks]);        \
        }                                                                      \
        _Pragma("unroll")                                                      \
        for (int ks = 0; ks < 4; ++ks) {                                       \
            ar = __builtin_amdgcn_mfma_f32_16x16x32_bf16(aH[0][ks], hF[ks], ar, 0, 0, 0); \
            az = __builtin_amdgcn_mfma_f32_16x16x32_bf16(aH[1][ks], hF[ks], az, 0, 0, 0); \
            ah = __builtin_amdgcn_mfma_f32_16x16x32_bf16(aH[2][ks], hF[ks], ah, 0, 0, 0); \
        }                                                                      \
        const float gr  = selq(ar, q);                                         \
        const float gz  = selq(az, q);                                         \
        const float gi_ = selq(ai, q);                                         \
        const float gh_ = selq(ah, q);                                         \
        const float rg  = __builtin_amdgcn_rcpf(1.f + __builtin_amdgcn_exp2f(-L2E * gr)); \
        const float zg  = __builtin_amdgcn_rcpf(1.f + __builtin_amdgcn_exp2f(-L2E * gz)); \
        const float nx  = gi_ + rg * gh_;                                      \
        const float ng  = 1.f - 2.f * __builtin_amdgcn_rcpf(1.f + __builtin_amdgcn_exp2f((2.f * L2E) * nx)); \
        const float hnew = ng + zg * (h_cur - ng);                             \
        h_cur = hnew;                                                          \
        hmx = fmaxf(hmx, hnew);                                                \
        *(unsigned short*)(h_lds[(P) ^ 1] + hw_off) = f2bf(hnew);              \
        __builtin_amdgcn_sched_barrier(0);                                     \
        asm volatile("s_waitcnt lgkmcnt(0)");                                  \
        __builtin_amdgcn_s_barrier();                                          \
        __builtin_amdgcn_sched_barrier(0);                                     \
    }

    for (int t = 0; t < S_; t += 2) {
        GRU_STEP(eC, eN, 0, t)
        GRU_STEP(eN, eC, 1, t + 1)
    }
#undef GRU_STEP

    if (j_own < 100)
        hmax_out[((size_t)((e * 2 + dir) * 64 + b0 + c)) * HH + j_own] = hmx;
}

// ---------------------------------------------------------------------------
// K4: fc + softmax — parallel (unchanged).
// ---------------------------------------------------------------------------
__global__ __launch_bounds__(512) void k_final(
    const float* __restrict__ hmax,
    const float* __restrict__ fcw,
    const float* __restrict__ fcb,
    float* __restrict__ out)
{
    const int tid  = threadIdx.x;
    const int b    = tid >> 3;
    const int part = tid & 7;
    float y0 = 0.f, y1 = 0.f;
    #pragma unroll 2
    for (int i = 0; i < 50; ++i) {
        const int m   = part * 50 + i;
        const int e   = m / 200;
        const int dm  = m % 200;
        const int dir = dm / 100;
        const int j   = dm % 100;
        const float x = hmax[((size_t)((e * 2 + dir) * 64 + b)) * HH + j];
        y0 += fcw[m]       * x;
        y1 += fcw[400 + m] * x;
    }
    #pragma unroll
    for (int m = 1; m < 8; m <<= 1) {
        y0 += __shfl_xor(y0, m);
        y1 += __shfl_xor(y1, m);
    }
    if (part == 0) {
        y0 += fcb[0]; y1 += fcb[1];
        const float mx = fmaxf(y0, y1);
        const float e0 = __expf(y0 - mx), e1 = __expf(y1 - mx);
        const float s = e0 + e1;
        out[b * 2]     = e0 / s;
        out[b * 2 + 1] = e1 / s;
    }
}

extern "C" void kernel_launch(void* const* d_in, const int* in_sizes, int n_in,
                              void* d_out, int out_size, void* d_ws, size_t ws_size,
                              hipStream_t stream)
{
    const int*   tok1  = (const int*)d_in[0];
    const int*   tok2  = (const int*)d_in[1];
    const float* emb   = (const float*)d_in[4];
    const float* Wc    = (const float*)d_in[5];
    const float* bc    = (const float*)d_in[6];
    const float* wih_f = (const float*)d_in[7];
    const float* whh_f = (const float*)d_in[8];
    const float* bih_f = (const float*)d_in[9];
    const float* bhh_f = (const float*)d_in[10];
    const float* wih_b = (const float*)d_in[11];
    const float* whh_b = (const float*)d_in[12];
    const float* bih_b = (const float*)d_in[13];
    const float* bhh_b = (const float*)d_in[14];
    const float* fcw   = (const float*)d_in[15];
    const float* fcb   = (const float*)d_in[16];

    char* ws = (char*)d_ws;
    unsigned short* emb_bf  = (unsigned short*)(ws + EMB_BF_OFF);
    unsigned short* wc_bf   = (unsigned short*)(ws + WC_BF_OFF);
    unsigned short* wih_pad = (unsigned short*)(ws + WIH_BF_OFF);
    unsigned short* whh_pad = (unsigned short*)(ws + WHH_BF_OFF);
    unsigned short* enc_bf  = (unsigned short*)(ws + ENC_BF_OFF);
    float*          hmax    = (float*)(ws + HMAX_OFF);

    k_prep<<<6458, 256, 0, stream>>>(emb, Wc, wih_f, wih_b, whh_f, whh_b,
                                     emb_bf, wc_bf, wih_pad, whh_pad);
    k_encode<<<2048, 512, 0, stream>>>(tok1, tok2, emb_bf, wc_bf, bc, enc_bf);
    k_gru<<<64, 448, 0, stream>>>(enc_bf, wih_pad, whh_pad,
                                  bih_f, bih_b, bhh_f, bhh_b, hmax);
    k_final<<<1, 512, 0, stream>>>(hmax, fcw, fcb, (float*)d_out);
}

// Round 18
// 133.083 us; speedup vs baseline: 1.0930x; 1.0930x over previous
//
#include <hip/hip_runtime.h>
#include <math.h>

#define B_      64
#define S_      128
#define KN      16
#define EE      128
#define HH      100
#define NTREE   8192            // B_*S_

typedef __attribute__((ext_vector_type(8))) short   bf8;    // 8 bf16 (4 VGPRs)
typedef __attribute__((ext_vector_type(2))) float   f32x2;
typedef __attribute__((ext_vector_type(4))) float   f32x4;
typedef __attribute__((ext_vector_type(4))) unsigned int u32x4;

// workspace byte offsets (256-aligned)
#define EMB_BF_OFF   0u           // 50000*128*2 = 12,800,000
#define WC_BF_OFF    12800000u    // 128*128*2   = 32,768
#define WIH_BF_OFF   12832768u    // 768*128*2   = 196,608 (padded [dir][g][128j][128k])
#define WHH_BF_OFF   13029376u    // 768*128*2   = 196,608 (padded, zero pads)
#define ENC_BF_OFF   13225984u    // 16384*128*2 = 4,194,304   rows = e*8192 + t*64 + b
#define HMAX_OFF     17420288u    // 25600*4     = 102,400
#define CNT_OFF      17522688u    // 4 bytes

__constant__ float c_cnt[16] = {16.f,8.f,7.f,4.f,3.f,3.f,3.f,2.f,
                                1.f,1.f,1.f,1.f,1.f,1.f,1.f,1.f};

__device__ __forceinline__ float bf2f(unsigned short u) {
    unsigned int x = ((unsigned int)u) << 16;
    return __builtin_bit_cast(float, x);
}
__device__ __forceinline__ unsigned short f2bf(float f) {
    unsigned int x = __builtin_bit_cast(unsigned int, f);
    x = x + 0x7fffu + ((x >> 16) & 1u);          // RNE
    return (unsigned short)(x >> 16);
}
__device__ __forceinline__ f32x2 up2(unsigned int u) {
    f32x2 v;
    v[0] = bf2f((unsigned short)(u & 0xffffu));
    v[1] = bf2f((unsigned short)(u >> 16));
    return v;
}
__device__ __forceinline__ unsigned int pack2(const f32x2& v) {
    return (unsigned int)f2bf(v[0]) | ((unsigned int)f2bf(v[1]) << 16);
}
__device__ __forceinline__ float selq(const f32x4& v, int q) {
    const float a = (q & 1) ? v[1] : v[0];
    const float b = (q & 1) ? v[3] : v[2];
    return (q & 2) ? b : a;
}
// swizzle a 16B-aligned column-byte offset within a 256B row
#define SWZ(row, cb) ((cb) ^ (((row) & 7) << 4))

// ---------------------------------------------------------------------------
// K0: fp32 -> bf16 prep: emb + Wc + wih/whh padded [2][3][128j][128k].
// Also resets the k_gru completion counter (graph-replay-safe).
// ---------------------------------------------------------------------------
#define NA 1600000   // emb float4s
#define NB 4096      // Wc float4s
#define NC 24576     // wih_pad ushort4s (768*128/4)
#define ND 24576     // whh_pad ushort4s
__global__ __launch_bounds__(256) void k_prep(
    const float* __restrict__ emb, const float* __restrict__ Wc,
    const float* __restrict__ wih_f, const float* __restrict__ wih_b,
    const float* __restrict__ whh_f, const float* __restrict__ whh_b,
    unsigned short* __restrict__ emb_bf, unsigned short* __restrict__ wc_bf,
    unsigned short* __restrict__ wih_pad, unsigned short* __restrict__ whh_pad,
    unsigned int* __restrict__ counter)
{
    const int i = blockIdx.x * 256 + threadIdx.x;
    if (i == 0) *counter = 0u;
    if (i < NA + NB) {
        const float* src = (i < NA) ? emb : Wc;
        unsigned short* dst = (i < NA) ? emb_bf : wc_bf;
        const int j = (i < NA) ? i : i - NA;
        float4 v = ((const float4*)src)[j];
        ushort4 o;
        o.x = f2bf(v.x); o.y = f2bf(v.y); o.z = f2bf(v.z); o.w = f2bf(v.w);
        ((ushort4*)dst)[j] = o;
    } else if (i < NA + NB + NC) {
        const int u = i - NA - NB;                  // 0..24575
        const int row = u >> 5, k4 = u & 31;        // row 0..767
        const int dir = row / 384, rem = row % 384, g = rem >> 7, j = rem & 127;
        ushort4 o = {0, 0, 0, 0};
        if (j < 100) {
            const float* w = dir ? wih_b : wih_f;   // [300][128]
            float4 v = ((const float4*)w)[(g * 100 + j) * 32 + k4];
            o.x = f2bf(v.x); o.y = f2bf(v.y); o.z = f2bf(v.z); o.w = f2bf(v.w);
        }
        ((ushort4*)wih_pad)[u] = o;
    } else if (i < NA + NB + NC + ND) {
        const int u = i - NA - NB - NC;
        const int row = u >> 5, k0 = (u & 31) * 4;
        const int dir = row / 384, rem = row % 384, g = rem >> 7, j = rem & 127;
        ushort4 o = {0, 0, 0, 0};
        if (j < 100) {
            const float* w = dir ? whh_b : whh_f;   // [300][100]
            const float* wr = w + (g * 100 + j) * 100;
            unsigned short t[4];
            #pragma unroll
            for (int q = 0; q < 4; ++q)
                t[q] = (k0 + q < 100) ? f2bf(wr[k0 + q]) : (unsigned short)0;
            o.x = t[0]; o.y = t[1]; o.z = t[2]; o.w = t[3];
        }
        ((ushort4*)whh_pad)[u] = o;
    }
}

// ---------------------------------------------------------------------------
// K1: REGISTER tree aggregation + bf16 emb gather + B_lds staging
// (R15-exact; R17's no-B_lds variant regressed).
// ---------------------------------------------------------------------------
__global__ __launch_bounds__(512) void k_encode(
    const int* __restrict__ tok1, const int* __restrict__ tok2,
    const unsigned short* __restrict__ emb_bf,
    const unsigned short* __restrict__ wc_bf,
    const float* __restrict__ bc,
    unsigned short* __restrict__ enc_bf)
{
    __shared__ unsigned short A_lds[128 * 128];   // [row][k] swizzled (32KB)
    __shared__ unsigned short B_lds[128 * 128];   // [col][k] swizzled (32KB)
    const int tid = threadIdx.x;
    const int blk = blockIdx.x;
    const int e = blk >> 10;
    const int tree0 = (blk & 1023) * 8;
    const int* __restrict__ tok = e ? tok2 : tok1;

    const int lane = tid & 63;
    const int tr = tid >> 6;         // tree 0..7 (== wave)
    const int sd = tid & 63;         // 2-dim segment: dims [2*sd, 2*sd+1]

    // stage Wc loads early
    u32x4 wcv[4];
    #pragma unroll
    for (int it = 0; it < 4; ++it) {
        const int idx = tid + 512 * it;          // 0..2047
        wcv[it] = *(const u32x4*)(wc_bf + (idx >> 4) * EE + (idx & 15) * 8);
    }

    // tokens (4 x int4 = all 16 nodes of this tree)
    const int4* tkp = (const int4*)(tok + (tree0 + tr) * KN);
    const int4 tkA = tkp[0], tkB = tkp[1], tkC = tkp[2], tkD = tkp[3];

    // gather 16 x u32 (2 bf16 dims each; 64 lanes x 4B = full row, coalesced)
#define LDE(tk) up2(*(const unsigned int*)(emb_bf + (size_t)(tk) * EE + sd * 2))
    f32x2 a0 = LDE(tkA.x), a1 = LDE(tkA.y), a2  = LDE(tkA.z), a3  = LDE(tkA.w);
    f32x2 a4 = LDE(tkB.x), a5 = LDE(tkB.y), a6  = LDE(tkB.z), a7  = LDE(tkB.w);
    f32x2 a8 = LDE(tkC.x), a9 = LDE(tkC.y), a10 = LDE(tkC.z), a11 = LDE(tkC.w);
    f32x2 a12 = LDE(tkD.x), a13 = LDE(tkD.y), a14 = LDE(tkD.z), a15 = LDE(tkD.w);
#undef LDE

    // bottom-up child-sum (pure VALU)
    a7 += a15;
    a3 += a7  + a8;   a4 += a9  + a10;
    a5 += a11 + a12;  a6 += a13 + a14;
    a1 += a3  + a4;   a2 += a5  + a6;
    a0 += a1  + a2;

    // write to A tile: 4B per node at swizzled chunk
    {
        const int cb = (sd >> 2) << 4;       // 16B chunk byte offset
        const int ib = (sd & 3) * 4;         // byte within chunk
        const int r0 = tr * 16;
#define STA(n, v) *(unsigned int*)((char*)A_lds + (r0 + (n)) * 256 \
                    + (cb ^ (((r0 + (n)) & 7) << 4)) + ib) = pack2(v);
        STA(0, a0)  STA(1, a1)  STA(2, a2)   STA(3, a3)
        STA(4, a4)  STA(5, a5)  STA(6, a6)   STA(7, a7)
        STA(8, a8)  STA(9, a9)  STA(10, a10) STA(11, a11)
        STA(12, a12) STA(13, a13) STA(14, a14) STA(15, a15)
#undef STA
    }
    #pragma unroll
    for (int it = 0; it < 4; ++it) {
        const int idx = tid + 512 * it;
        const int row = idx >> 4, sg = idx & 15;
        *(u32x4*)((char*)B_lds + row * 256 + SWZ(row, sg * 16)) = wcv[it];
    }
    __syncthreads();

    const int wid = tid >> 6;
    const int wr = wid >> 1, wc = wid & 1;
    const int l15 = lane & 15, lg = lane >> 4;

    f32x4 acc[2][4];
    #pragma unroll
    for (int rt = 0; rt < 2; ++rt)
        #pragma unroll
        for (int ct = 0; ct < 4; ++ct) acc[rt][ct] = (f32x4){0.f, 0.f, 0.f, 0.f};

    #pragma unroll
    for (int ks = 0; ks < 4; ++ks) {
        bf8 aF[2], bF[4];
        #pragma unroll
        for (int rt = 0; rt < 2; ++rt) {
            const int row = wr * 32 + rt * 16 + l15;
            aF[rt] = *(const bf8*)((const char*)A_lds + row * 256 + SWZ(row, ks * 64 + lg * 16));
        }
        #pragma unroll
        for (int ct = 0; ct < 4; ++ct) {
            const int col = wc * 64 + ct * 16 + l15;
            bF[ct] = *(const bf8*)((const char*)B_lds + col * 256 + SWZ(col, ks * 64 + lg * 16));
        }
        #pragma unroll
        for (int rt = 0; rt < 2; ++rt)
            #pragma unroll
            for (int ct = 0; ct < 4; ++ct)
                acc[rt][ct] = __builtin_amdgcn_mfma_f32_16x16x32_bf16(aF[rt], bF[ct], acc[rt][ct], 0, 0, 0);
    }

    #pragma unroll
    for (int rt = 0; rt < 2; ++rt) {
        const int ltree = wr * 2 + rt;
        #pragma unroll
        for (int ct = 0; ct < 4; ++ct) {
            const int col = wc * 64 + ct * 16 + l15;
            const float bcv = bc[col];
            f32x4 v = acc[rt][ct];
            float m = -1e30f;
            #pragma unroll
            for (int r = 0; r < 4; ++r)
                m = fmaxf(m, v[r] + c_cnt[lg * 4 + r] * bcv);
            m = fmaxf(m, __shfl_xor(m, 16));
            m = fmaxf(m, __shfl_xor(m, 32));
            m = fmaxf(m, 0.f);
            if (lg == 0) {
                const int gtree = tree0 + ltree;
                const int row = (gtree & 127) * 64 + (gtree >> 7);   // t*64 + b
                enc_bf[((size_t)e * NTREE + row) * EE + col] = f2bf(m);
            }
        }
    }
}

// ---------------------------------------------------------------------------
// K3: LDS-resident GRU scan (R13-exact loop) + FUSED fc/softmax epilogue:
// each block bumps a device counter after its hmax stores; the 64th block
// performs the final 400-term FC + softmax across its 448 threads.
// ---------------------------------------------------------------------------
__global__ __launch_bounds__(448, 2) void k_gru(
    const unsigned short* __restrict__ enc_bf,
    const unsigned short* __restrict__ wih_pad,
    const unsigned short* __restrict__ whh_pad,
    const float* __restrict__ bih_f, const float* __restrict__ bih_b,
    const float* __restrict__ bhh_f, const float* __restrict__ bhh_b,
    float* __restrict__ hmax_out,
    const float* __restrict__ fcw, const float* __restrict__ fcb,
    float* __restrict__ out, unsigned int* __restrict__ counter)
{
    __shared__ unsigned char enc_lds[4 * 128 * 256];  // 128KB [c][t][chunk^(c<<2)]
    __shared__ unsigned char h_lds[2][4 * 256];       // 2KB dbuf, rotated chunks
    __shared__ int last_flag;
    const int tid  = threadIdx.x;
    const int blk  = blockIdx.x;        // 64
    const int e    = blk >> 5;
    const int dir  = (blk >> 4) & 1;
    const int b0   = (blk & 15) * 4;
    const int lane = tid & 63;
    const int l15  = lane & 15;
    const int lg   = lane >> 4;
    const int c    = l15 & 3;           // seq column
    const int q    = l15 >> 2;          // owned r-slot (gate split)
    const int jbase = (tid >> 6) * 16;
    const int j_own = jbase + lg * 4 + q;

    for (int u = tid; u < 512; u += 448)
        ((unsigned int*)h_lds)[u] = 0u;

    // stage enc slice into LDS (content chunk = rc ^ (c<<2))
    #pragma unroll
    for (int i = 0; i < 19; ++i) {
        const int s = tid + i * 448;
        if (s < 8192) {
            const int sc = s >> 11, st = (s >> 4) & 127, rc = s & 15;
            const int gch = rc ^ (sc << 2);
            const u32x4 v = *(const u32x4*)(enc_bf
                + ((size_t)e * NTREE + st * 64 + b0 + sc) * EE + gch * 8);
            *(u32x4*)(enc_lds + s * 16) = v;
        }
    }

    // weight A-frags: row j = jbase + l15, k = ks*32 + lg*8
    bf8 aI[3][4], aH[3][4];
    {
        const unsigned short* wiP = wih_pad + (size_t)dir * 3 * 128 * 128;
        const unsigned short* whP = whh_pad + (size_t)dir * 3 * 128 * 128;
        #pragma unroll
        for (int g = 0; g < 3; ++g)
            #pragma unroll
            for (int ks = 0; ks < 4; ++ks) {
                const size_t ro = (size_t)(g * 128 + jbase + l15) * 128 + ks * 32 + lg * 8;
                aI[g][ks] = *(const bf8*)(wiP + ro);
                aH[g][ks] = *(const bf8*)(whP + ro);
            }
    }
    const float* __restrict__ bih = dir ? bih_b : bih_f;
    const float* __restrict__ bhh = dir ? bhh_b : bhh_f;
    f32x4 bR, bZ, bI_, bH_;
    #pragma unroll
    for (int r = 0; r < 4; ++r) {
        const int j = jbase + lg * 4 + r;
        bR[r]  = (j < 100) ? bih[j]       + bhh[j]       : 0.f;
        bZ[r]  = (j < 100) ? bih[100 + j] + bhh[100 + j] : 0.f;
        bI_[r] = (j < 100) ? bih[200 + j] : 0.f;
        bH_[r] = (j < 100) ? bhh[200 + j] : 0.f;
    }

    // constant per-lane LDS offsets
    unsigned int eoff[4], hoff[4];
    #pragma unroll
    for (int ks = 0; ks < 4; ++ks) {
        eoff[ks] = c * 32768 + ((((ks * 4 + lg) ^ (c << 2)) & 15) << 4);
        hoff[ks] = c * 256 + (((ks * 4 + lg + 4 * c) & 15) << 4);
    }
    const unsigned int hw_off = c * 256
        + ((((j_own >> 3) + 4 * c) & 15) << 4) + (j_own & 7) * 2;

    float h_cur = 0.f;
    float hmx   = -1e30f;
    __syncthreads();   // staging + h-zero complete (one-time drain)

    bf8 eC[4], eN[4];
    {
        const int tm = dir ? 127 : 0;
        #pragma unroll
        for (int ks = 0; ks < 4; ++ks)
            eC[ks] = *(const bf8*)(enc_lds + tm * 256 + eoff[ks]);
    }

#define L2E  1.4426950408889634f
#define GRU_STEP(EC, EN, P, S)                                                 \
    {                                                                          \
        bf8 hF[4];                                                             \
        _Pragma("unroll")                                                      \
        for (int ks = 0; ks < 4; ++ks)                                         \
            hF[ks] = *(const bf8*)(h_lds[P] + hoff[ks]);                       \
        f32x4 ar = bR, az = bZ, ai = bI_, ah = bH_;                            \
        _Pragma("unroll")                                                      \
        for (int ks = 0; ks < 4; ++ks) {                                       \
            ar = __builtin_amdgcn_mfma_f32_16x16x32_bf16(aI[0][ks], EC[ks], ar, 0, 0, 0); \
            az = __builtin_amdgcn_mfma_f32_16x16x32_bf16(aI[1][ks], EC[ks], az, 0, 0, 0); \
            ai = __builtin_amdgcn_mfma_f32_16x16x32_bf16(aI[2][ks], EC[ks], ai, 0, 0, 0); \
        }                                                                      \
        if ((S) + 1 < S_) {                                                    \
            const int tmn = dir ? (126 - (S)) : ((S) + 1);                     \
            _Pragma("unroll")                                                  \
            for (int ks = 0; ks < 4; ++ks)                                     \
                EN[ks] = *(const bf8*)(enc_lds + tmn * 256 + eoff[ks]);        \
        }                                                                      \
        _Pragma("unroll")                                                      \
        for (int ks = 0; ks < 4; ++ks) {                                       \
            ar = __builtin_amdgcn_mfma_f32_16x16x32_bf16(aH[0][ks], hF[ks], ar, 0, 0, 0); \
            az = __builtin_amdgcn_mfma_f32_16x16x32_bf16(aH[1][ks], hF[ks], az, 0, 0, 0); \
            ah = __builtin_amdgcn_mfma_f32_16x16x32_bf16(aH[2][ks], hF[ks], ah, 0, 0, 0); \
        }                                                                      \
        const float gr  = selq(ar, q);                                         \
        const float gz  = selq(az, q);                                         \
        const float gi_ = selq(ai, q);                                         \
        const float gh_ = selq(ah, q);                                         \
        const float rg  = __builtin_amdgcn_rcpf(1.f + __builtin_amdgcn_exp2f(-L2E * gr)); \
        const float zg  = __builtin_amdgcn_rcpf(1.f + __builtin_amdgcn_exp2f(-L2E * gz)); \
        const float nx  = gi_ + rg * gh_;                                      \
        const float ng  = 1.f - 2.f * __builtin_amdgcn_rcpf(1.f + __builtin_amdgcn_exp2f((2.f * L2E) * nx)); \
        const float hnew = ng + zg * (h_cur - ng);                             \
        h_cur = hnew;                                                          \
        hmx = fmaxf(hmx, hnew);                                                \
        *(unsigned short*)(h_lds[(P) ^ 1] + hw_off) = f2bf(hnew);              \
        __builtin_amdgcn_sched_barrier(0);                                     \
        asm volatile("s_waitcnt lgkmcnt(0)");                                  \
        __builtin_amdgcn_s_barrier();                                          \
        __builtin_amdgcn_sched_barrier(0);                                     \
    }

    for (int t = 0; t < S_; t += 2) {
        GRU_STEP(eC, eN, 0, t)
        GRU_STEP(eN, eC, 1, t + 1)
    }
#undef GRU_STEP

    if (j_own < 100)
        hmax_out[((size_t)((e * 2 + dir) * 64 + b0 + c)) * HH + j_own] = hmx;

    // --- fused final: last block to finish does fc + softmax ---
    __threadfence();
    __syncthreads();
    if (tid == 0) {
        const unsigned int old = atomicAdd(counter, 1u);
        last_flag = (old == 63u);
    }
    __syncthreads();
    if (last_flag) {
        __threadfence();          // acquire others' hmax stores
        float* red = (float*)enc_lds;       // reuse LDS: [part][b][2]
        const int b    = tid & 63;
        const int part = tid >> 6;          // 0..6
        float y0 = 0.f, y1 = 0.f;
        for (int i = 0; i < 58; ++i) {
            const int m = part * 58 + i;
            if (m < 400) {
                const int em  = m / 200;
                const int dm  = m % 200;
                const int dr  = dm / 100;
                const int j   = dm % 100;
                const float x = hmax_out[((size_t)((em * 2 + dr) * 64 + b)) * HH + j];
                y0 += fcw[m]       * x;
                y1 += fcw[400 + m] * x;
            }
        }
        red[(part * 64 + b) * 2 + 0] = y0;
        red[(part * 64 + b) * 2 + 1] = y1;
        __syncthreads();
        if (tid < 64) {
            float s0 = fcb[0], s1 = fcb[1];
            #pragma unroll
            for (int p = 0; p < 7; ++p) {
                s0 += red[(p * 64 + tid) * 2 + 0];
                s1 += red[(p * 64 + tid) * 2 + 1];
            }
            const float mx = fmaxf(s0, s1);
            const float e0 = __expf(s0 - mx), e1 = __expf(s1 - mx);
            const float sm = e0 + e1;
            out[tid * 2]     = e0 / sm;
            out[tid * 2 + 1] = e1 / sm;
        }
    }
}

extern "C" void kernel_launch(void* const* d_in, const int* in_sizes, int n_in,
                              void* d_out, int out_size, void* d_ws, size_t ws_size,
                              hipStream_t stream)
{
    const int*   tok1  = (const int*)d_in[0];
    const int*   tok2  = (const int*)d_in[1];
    const float* emb   = (const float*)d_in[4];
    const float* Wc    = (const float*)d_in[5];
    const float* bc    = (const float*)d_in[6];
    const float* wih_f = (const float*)d_in[7];
    const float* whh_f = (const float*)d_in[8];
    const float* bih_f = (const float*)d_in[9];
    const float* bhh_f = (const float*)d_in[10];
    const float* wih_b = (const float*)d_in[11];
    const float* whh_b = (const float*)d_in[12];
    const float* bih_b = (const float*)d_in[13];
    const float* bhh_b = (const float*)d_in[14];
    const float* fcw   = (const float*)d_in[15];
    const float* fcb   = (const float*)d_in[16];

    char* ws = (char*)d_ws;
    unsigned short* emb_bf  = (unsigned short*)(ws + EMB_BF_OFF);
    unsigned short* wc_bf   = (unsigned short*)(ws + WC_BF_OFF);
    unsigned short* wih_pad = (unsigned short*)(ws + WIH_BF_OFF);
    unsigned short* whh_pad = (unsigned short*)(ws + WHH_BF_OFF);
    unsigned short* enc_bf  = (unsigned short*)(ws + ENC_BF_OFF);
    float*          hmax    = (float*)(ws + HMAX_OFF);
    unsigned int*   counter = (unsigned int*)(ws + CNT_OFF);

    k_prep<<<6458, 256, 0, stream>>>(emb, Wc, wih_f, wih_b, whh_f, whh_b,
                                     emb_bf, wc_bf, wih_pad, whh_pad, counter);
    k_encode<<<2048, 512, 0, stream>>>(tok1, tok2, emb_bf, wc_bf, bc, enc_bf);
    k_gru<<<64, 448, 0, stream>>>(enc_bf, wih_pad, whh_pad,
                                  bih_f, bih_b, bhh_f, bhh_b, hmax,
                                  fcw, fcb, (float*)d_out, counter);
}